// Round 8
// baseline (144.437 us; speedup 1.0000x reference)
//
#include <hip/hip_runtime.h>
#include <hip/hip_bf16.h>
#include <math.h>

#define BATCH 64
#define TT 512
#define HH 1024
#define KK 8
#define ROWS (BATCH * TT)          // 32768
#define SEG  (ROWS * KK)           // 262144 floats per logits output
#define TAGS_OFF (3 * SEG)         // 786432
#define LOSS_OFF (TAGS_OFF + BATCH * 3 * TT)  // 884736

// ---------------------------------------------------------------------------
// Kernel 1: fused 3-head GEMM. 512 blocks x 4 waves, K-quarter per wave.
// R7 found the weight broadcast ds_read_b128 costs full per-lane DS slots
// (~12 cyc each, 6/stage = DS-pipe-bound). R8: weights distributed across
// lanes ONCE per it (2 x b128/lane), broadcast per stage via v_readlane
// (VALU, SGPR dest) feeding v_fmac with SGPR operand -> stage loop is pure
// VALU; DS pipe ~idle.
// ---------------------------------------------------------------------------
#define XL(wv, buf, hh, col) smem[(((wv) * 2 + (buf)) * 16 + (hh)) * 68 + (col)]

__device__ __forceinline__ float bcast(float v, int srcLane) {
#if __has_builtin(__builtin_amdgcn_readlane)
    return __int_as_float(__builtin_amdgcn_readlane(__float_as_int(v), srcLane));
#else
    return __shfl(v, srcLane);
#endif
}

__device__ __forceinline__ float wsel(const float4& a, const float4& b, int k) {
    switch (k) {
    case 0: return a.x; case 1: return a.y; case 2: return a.z; case 3: return a.w;
    case 4: return b.x; case 5: return b.y; case 6: return b.z; default: return b.w;
    }
}

__global__ __launch_bounds__(256, 2) void gemm_heads(
    const float* __restrict__ enc,
    const float* __restrict__ Wt, const float* __restrict__ bt,
    const float* __restrict__ Wp, const float* __restrict__ bpv,
    const float* __restrict__ Wm, const float* __restrict__ bm,
    float* __restrict__ out)
{
    __shared__ float smem[4 * 2 * 16 * 68];   // 34.8 KB x tiles; red overlays
    __shared__ float wl[4][2][16][24];        // 12.3 KB weight tiles

    int tid  = threadIdx.x;
    int lane = tid & 63;
    int wv   = __builtin_amdgcn_readfirstlane(tid >> 6);
    int rowbase = blockIdx.x * 64;
    const float* encb = enc + (size_t)rowbase * HH + wv * 256;
    const float* Wqt = Wt + wv * 2048;        // quarter base: 256 rows x 8
    const float* Wqp = Wp + wv * 2048;
    const float* Wqm = Wm + wv * 2048;

    int srow = lane >> 2;
    int sslot = lane & 3;
    int wrow = lane >> 3;        // weight LDS row (0..7), +8 for second word
    int wcol = lane & 7;
    int whead = (lane & 3) == 3 ? 2 : (lane & 3);  // lane holds W(h=lane>>2, head)

    float acc[24];
#pragma unroll
    for (int c = 0; c < 24; ++c) acc[c] = 0.f;

    float4 sreg[4];
    float  wreg[6];

#define LOADT(it)                                                             \
    {                                                                         \
        _Pragma("unroll")                                                     \
        for (int j = 0; j < 4; ++j)                                           \
            sreg[j] = *(const float4*)(encb + (size_t)(srow + 16 * j) * HH +  \
                                       (it) * 16 + sslot * 4);                \
    }
#define WRITET(buf)                                                           \
    {                                                                         \
        _Pragma("unroll")                                                     \
        for (int j = 0; j < 4; ++j) {                                         \
            XL(wv, buf, sslot * 4 + 0, srow + 16 * j) = sreg[j].x;            \
            XL(wv, buf, sslot * 4 + 1, srow + 16 * j) = sreg[j].y;            \
            XL(wv, buf, sslot * 4 + 2, srow + 16 * j) = sreg[j].z;            \
            XL(wv, buf, sslot * 4 + 3, srow + 16 * j) = sreg[j].w;            \
        }                                                                     \
    }
// per it-tile: 384 floats (16h x 24 outputs); lane loads word `lane` and
// `lane+64` of each head's 128-float contiguous tile -> fully coalesced.
#define WLOADG(it)                                                            \
    {                                                                         \
        const float* pt_ = Wqt + (it) * 128;                                  \
        const float* pp_ = Wqp + (it) * 128;                                  \
        const float* pm_ = Wqm + (it) * 128;                                  \
        wreg[0] = pt_[lane]; wreg[1] = pt_[64 + lane];                        \
        wreg[2] = pp_[lane]; wreg[3] = pp_[64 + lane];                        \
        wreg[4] = pm_[lane]; wreg[5] = pm_[64 + lane];                        \
    }
// word g of a head tile (g = hh*8+c) -> wl[..][hh][head*8+c]
#define WWRITE(buf)                                                           \
    {                                                                         \
        wl[wv][buf][wrow][wcol]          = wreg[0];                           \
        wl[wv][buf][8 + wrow][wcol]      = wreg[1];                           \
        wl[wv][buf][wrow][8 + wcol]      = wreg[2];                           \
        wl[wv][buf][8 + wrow][8 + wcol]  = wreg[3];                           \
        wl[wv][buf][wrow][16 + wcol]     = wreg[4];                           \
        wl[wv][buf][8 + wrow][16 + wcol] = wreg[5];                           \
    }

    LOADT(0)
    WLOADG(0)
    WRITET(0)
    WWRITE(0)

    for (int it = 0; it < 16; ++it) {
        int cb = it & 1;
        if (it < 15) {                        // issue next tile's loads early
            LOADT(it + 1)
            WLOADG(it + 1)
        }

        // distribute this it's weights across lanes: 8 floats/lane (32 B)
        const float4* wsp = (const float4*)&wl[wv][cb][lane >> 2][whead * 8];
        float4 ws0 = wsp[0];
        float4 ws1 = wsp[1];

#pragma unroll
        for (int hh = 0; hh < 16; ++hh) {
            float x = XL(wv, cb, hh, lane);
#pragma unroll
            for (int c = 0; c < 24; ++c) {
                // weight w[hh][c] lives in lane 4*hh + (c>>3), reg slot c&7
                float w = bcast(wsel(ws0, ws1, c & 7), 4 * hh + (c >> 3));
                acc[c] = fmaf(x, w, acc[c]);
            }
        }
        if (it < 15) {                        // write-late; per-wave private
            WRITET(cb ^ 1)
            WWRITE(cb ^ 1)
        }
    }
#undef LOADT
#undef WRITET
#undef WLOADG
#undef WWRITE

    __syncthreads();                          // all waves done with x tiles
    float* red = smem;                        // overlay: [3][64][25]
    if (wv != 0) {
#pragma unroll
        for (int c = 0; c < 24; ++c) red[((wv - 1) * 64 + lane) * 25 + c] = acc[c];
    }
    __syncthreads();
    if (wv == 0) {
        float s[24];
#pragma unroll
        for (int c = 0; c < 24; ++c)
            s[c] = acc[c] + red[(0 * 64 + lane) * 25 + c]
                          + red[(1 * 64 + lane) * 25 + c]
                          + red[(2 * 64 + lane) * 25 + c];
        size_t row = rowbase + lane;
        float* o0 = out + row * 8;
        float* o1 = out + SEG + row * 8;
        float* o2 = out + 2 * (size_t)SEG + row * 8;
        ((float4*)o0)[0] = make_float4(s[0] + bt[0],  s[1] + bt[1],  s[2] + bt[2],  s[3] + bt[3]);
        ((float4*)o0)[1] = make_float4(s[4] + bt[4],  s[5] + bt[5],  s[6] + bt[6],  s[7] + bt[7]);
        ((float4*)o1)[0] = make_float4(s[8] + bpv[0], s[9] + bpv[1], s[10] + bpv[2], s[11] + bpv[3]);
        ((float4*)o1)[1] = make_float4(s[12] + bpv[4], s[13] + bpv[5], s[14] + bpv[6], s[15] + bpv[7]);
        ((float4*)o2)[0] = make_float4(s[16] + bm[0], s[17] + bm[1], s[18] + bm[2], s[19] + bm[3]);
        ((float4*)o2)[1] = make_float4(s[20] + bm[4], s[21] + bm[5], s[22] + bm[6], s[23] + bm[7]);
    }
}

// ---------------------------------------------------------------------------
// Pure-VALU cross-lane helpers
// ---------------------------------------------------------------------------
#define DPPF(x, ctrl) __int_as_float(__builtin_amdgcn_update_dpp(              \
    0, __float_as_int(x), ctrl, 0xF, 0xF, true))
#define SWIZF(x, pat) __int_as_float(__builtin_amdgcn_ds_swizzle(              \
    __float_as_int(x), pat))
#define BPERMF(a, x)  __int_as_float(__builtin_amdgcn_ds_bpermute(             \
    a, __float_as_int(x)))

__device__ __forceinline__ float rfl(float x) {
    return __int_as_float(__builtin_amdgcn_readfirstlane(__float_as_int(x)));
}

#if __has_builtin(__builtin_amdgcn_permlane16_swap)
__device__ __forceinline__ float xor16f(float x, int lane) {
    typedef unsigned uv2 __attribute__((ext_vector_type(2)));
    uv2 r = __builtin_amdgcn_permlane16_swap(__float_as_uint(x), __float_as_uint(x), false, false);
    return __uint_as_float((lane & 16) ? r.x : r.y);
}
#else
__device__ __forceinline__ float xor16f(float x, int lane) { return SWIZF(x, 0x401F); }
#endif

#if __has_builtin(__builtin_amdgcn_permlane32_swap)
__device__ __forceinline__ float xor32f(float x, int lane) {
    typedef unsigned uv2 __attribute__((ext_vector_type(2)));
    uv2 r = __builtin_amdgcn_permlane32_swap(__float_as_uint(x), __float_as_uint(x), false, false);
    return __uint_as_float((lane & 32) ? r.x : r.y);
}
#else
__device__ __forceinline__ float xor32f(float x, int lane) {
    return BPERMF(((lane ^ 32) << 2), x);
}
#endif

// ---------------------------------------------------------------------------
// Kernel 2: 192 blocks x 128 threads (2 waves). Wave 0: Viterbi (bit-exact,
// ballot argmax, chunked backtrack). Wave 1: CRF logZ in multiplicative form
// (no exp/log on the recurrence chain) + scores. (R5-R7 version, proven.)
// ---------------------------------------------------------------------------
__global__ __launch_bounds__(128) void crf_vit(
    const float* __restrict__ logits,
    const int* __restrict__ labels,
    const int* __restrict__ lens,
    const float* __restrict__ trans_t,
    const float* __restrict__ trans_p,
    const float* __restrict__ trans_m,
    float* __restrict__ out_tags,
    float* __restrict__ partial)
{
    __shared__ float llds[TT * KK];        // 16 KB
    __shared__ unsigned bpw[TT * 2];       // 4 KB backpointers (wave-0 private)
    __shared__ unsigned fmapw[64][2];
    __shared__ unsigned char bnd[64];

    int blk = blockIdx.x;
    int h   = blk >> 6;
    int b   = blk & 63;
    int tid = threadIdx.x;
    int wid = __builtin_amdgcn_readfirstlane(tid >> 6);
    int lane = tid & 63;
    int hi = lane >> 3, lo = lane & 7;
    unsigned char* bpb = (unsigned char*)bpw;

    const float* L = logits + ((size_t)h * BATCH + b) * (TT * KK);
    const float4* Lv = (const float4*)L;
    float4* lv = (float4*)llds;
#pragma unroll
    for (int i = 0; i < 8; ++i) lv[tid + 128 * i] = Lv[tid + 128 * i];
    __syncthreads();

    const float* TR = (h == 0) ? trans_t : (h == 1) ? trans_p : trans_m;
    int len = lens[b];
    float trA = TR[lo * 8 + hi];   // even step: kp=lo -> kn=hi
    float trB = TR[hi * 8 + lo];   // odd step:  kp=hi -> kn=lo

    if (wid == 0) {
        // ================= Viterbi wave (bit-exact) =================
        float av = llds[lo];

#define VIT_EVEN(t, LT)                                                        \
    {                                                                          \
        float v0 = av + trA;                                                   \
        float ra = fmaxf(v0, DPPF(v0, 0xB1));                                  \
        float rb = fmaxf(ra, DPPF(ra, 0x4E));                                  \
        float vmax = fmaxf(rb, DPPF(rb, 0x141));                               \
        unsigned long long mk = __ballot(v0 == vmax);                          \
        int vi = __builtin_ctz(((unsigned)(mk >> (lane & 56))) & 0xffu);       \
        if (lo == 0) bpb[(t) * 8 + hi] = (unsigned char)vi;                    \
        av = vmax + (LT);                                                      \
    }
#define VIT_ODD(t, LT)                                                         \
    {                                                                          \
        float v0 = av + trB;                                                   \
        float ra = fmaxf(v0, DPPF(v0, 0x128));                                 \
        float rb = fmaxf(ra, xor16f(ra, lane));                                \
        float vmax = fmaxf(rb, xor32f(rb, lane));                              \
        unsigned long long mk = __ballot(v0 == vmax);                          \
        unsigned long long sel = (mk >> lo) & 0x0101010101010101ULL;           \
        int vi = __builtin_ctzll(sel) >> 3;                                    \
        if (hi == 0) bpb[(t) * 8 + lo] = (unsigned char)vi;                    \
        av = vmax + (LT);                                                      \
    }

        float ltA = llds[8 + hi];
        float ltB = llds[16 + lo];
        for (int t = 1; t <= 509; t += 2) {
            float ltA2 = llds[(t + 2) * 8 + hi];
            int tb = (t + 3 <= 511) ? (t + 3) : 511;
            float ltB2 = llds[tb * 8 + lo];
            VIT_EVEN(t, ltA);
            VIT_ODD(t + 1, ltB);
            ltA = ltA2; ltB = ltB2;
        }
        VIT_EVEN(511, ltA);
#undef VIT_EVEN
#undef VIT_ODD

        float ra = fmaxf(av, DPPF(av, 0x128));
        float rb = fmaxf(ra, xor16f(ra, lane));
        float vmax = fmaxf(rb, xor32f(rb, lane));
        unsigned long long mk = __ballot(av == vmax);
        int last_ = __builtin_ctzll(mk) >> 3;

        asm volatile("" ::: "memory");

        // Phase A: lane l composes bp maps for t in [8l+1, 8l+8]
        int t0 = lane * 8;
        unsigned rw[16];
#pragma unroll
        for (int j = 0; j < 8; ++j) {
            int t = t0 + 1 + j;
            if (t <= 511) { rw[2 * j] = bpw[t * 2]; rw[2 * j + 1] = bpw[t * 2 + 1]; }
            else          { rw[2 * j] = 0x03020100u; rw[2 * j + 1] = 0x07060504u; }
        }
        unsigned sv[8];
#pragma unroll
        for (int i = 0; i < 8; ++i) sv[i] = i;
#pragma unroll
        for (int j = 7; j >= 0; --j) {
            unsigned d0 = rw[2 * j], d1 = rw[2 * j + 1];
#pragma unroll
            for (int i = 0; i < 8; ++i) {
                unsigned s = sv[i];
                unsigned d = (s < 4) ? d0 : d1;
                sv[i] = (d >> (8 * (s & 3))) & 0xffu;
            }
        }
        fmapw[lane][0] = sv[0] | (sv[1] << 8) | (sv[2] << 16) | (sv[3] << 24);
        fmapw[lane][1] = sv[4] | (sv[5] << 8) | (sv[6] << 16) | (sv[7] << 24);
        asm volatile("" ::: "memory");

        if (lane == 0) {
            unsigned cur = (unsigned)last_;
            for (int l = 63; l >= 0; --l) {
                unsigned d = (cur < 4) ? fmapw[l][0] : fmapw[l][1];
                cur = (d >> (8 * (cur & 3))) & 0xffu;
                bnd[l] = (unsigned char)cur;
            }
        }
        asm volatile("" ::: "memory");

        int off = h * 8;
        float* otag = out_tags + b * (3 * TT) + h * TT;
        unsigned curr = (lane == 63) ? (unsigned)last_ : (unsigned)bnd[lane + 1];
#pragma unroll
        for (int j = 7; j >= 0; --j) {
            unsigned d = (curr < 4) ? rw[2 * j] : rw[2 * j + 1];
            curr = (d >> (8 * (curr & 3))) & 0xffu;
            otag[t0 + j] = (float)((int)curr + off);
        }
    } else {
        // ============ CRF wave: multiplicative logsumexp ============
        float EA = __expf(trA);
        float EB = __expf(trB);
        float al0 = llds[lo];
        float c0 = rfl(al0);
        float S = __expf(al0 - c0);
        float Mc = c0;
        float r1 = 0.f, r2 = 0.f, r3 = 0.f;
        const float LN8 = 2.0794415416798357f;

#define LSE_EVEN(t, LT)                                                        \
    {                                                                          \
        float c = rfl(LT) + LN8;                                               \
        float F = __expf((LT) - c);                                            \
        float P = S * EA;                                                      \
        float sa = P + DPPF(P, 0xB1);                                          \
        float sb = sa + DPPF(sa, 0x4E);                                        \
        float ss = sb + DPPF(sb, 0x141);                                       \
        if ((t) < len) { S = ss * F; Mc += c; }                                \
        r1 = r2; r2 = r3; r3 = __logf(rfl(S));                                 \
    }
#define LSE_ODD(t, LT)                                                         \
    {                                                                          \
        float c = rfl(LT) + LN8;                                               \
        float F = __expf((LT) - c);                                            \
        float P = S * EB;                                                      \
        float sa = P + DPPF(P, 0x128);                                         \
        float sb = sa + xor16f(sa, lane);                                      \
        float ss = sb + xor32f(sb, lane);                                      \
        if ((t) < len) { S = ss * F; Mc += c; }                                \
        r1 = r2; r2 = r3; r3 = __logf(rfl(S));                                 \
    }

        float ltA = llds[8 + hi];
        float ltB = llds[16 + lo];
        for (int t = 1; t <= 509; t += 2) {
            if ((t & 3) == 1) {
                float g = r2;
                S *= __expf(-g);
                Mc += g;
            }
            float ltA2 = llds[(t + 2) * 8 + hi];
            int tb = (t + 3 <= 511) ? (t + 3) : 511;
            float ltB2 = llds[tb * 8 + lo];
            LSE_EVEN(t, ltA);
            LSE_ODD(t + 1, ltB);
            ltA = ltA2; ltB = ltB2;
        }
        LSE_EVEN(511, ltA);
#undef LSE_EVEN
#undef LSE_ODD

        float aj = Mc + __logf(S);
        float za = fmaxf(aj, DPPF(aj, 0x128));
        float zb = fmaxf(za, xor16f(za, lane));
        float zmax = fmaxf(zb, xor32f(zb, lane));
        float ze = __expf(aj - zmax);
        float zs = ze + DPPF(ze, 0x128);
        float zs2 = zs + xor16f(zs, lane);
        float zsum = zs2 + xor32f(zs2, lane);
        float logZ = zmax + __logf(zsum);

        const int* lab = labels + b * (3 * TT) + h * TT;
        int off = h * 8;
        float sc = 0.f;
#pragma unroll
        for (int j = 0; j < 8; ++j) {
            int t = lane + 64 * j;
            if (t < len) {
                int tg = lab[t] - off;
                sc += llds[t * 8 + tg];
                if (t >= 1) {
                    int tp = lab[t - 1] - off;
                    sc += TR[tp * 8 + tg];
                }
            }
        }
#pragma unroll
        for (int d = 1; d <= 32; d <<= 1) sc += __shfl_xor(sc, d);

        if (lane == 0) partial[blk] = logZ - sc;
    }
}

// ---------------------------------------------------------------------------
// Kernel 3: deterministic loss reduction (192 partials -> scalar)
// ---------------------------------------------------------------------------
__global__ __launch_bounds__(64) void loss_reduce(
    const float* __restrict__ partial, float* __restrict__ out_loss)
{
    int lane = threadIdx.x;
    float s = partial[lane] + partial[lane + 64] + partial[lane + 128];
#pragma unroll
    for (int d = 1; d <= 32; d <<= 1) s += __shfl_xor(s, d);
    if (lane == 0) *out_loss = s;
}

// ---------------------------------------------------------------------------
extern "C" void kernel_launch(void* const* d_in, const int* in_sizes, int n_in,
                              void* d_out, int out_size, void* d_ws, size_t ws_size,
                              hipStream_t stream) {
    const float* enc    = (const float*)d_in[0];
    const int*   labels = (const int*)d_in[1];
    const int*   lens   = (const int*)d_in[2];
    const float* Wt     = (const float*)d_in[3];
    const float* bt     = (const float*)d_in[4];
    const float* Wp     = (const float*)d_in[5];
    const float* bpv    = (const float*)d_in[6];
    const float* Wm     = (const float*)d_in[7];
    const float* bm     = (const float*)d_in[8];
    const float* tr_t   = (const float*)d_in[9];
    const float* tr_p   = (const float*)d_in[10];
    const float* tr_m   = (const float*)d_in[11];

    float* out = (float*)d_out;
    float* partial = (float*)d_ws;   // 192 floats

    gemm_heads<<<ROWS / 64, 256, 0, stream>>>(enc, Wt, bt, Wp, bpv, Wm, bm, out);
    crf_vit<<<192, 128, 0, stream>>>(out, labels, lens, tr_t, tr_p, tr_m,
                                     out + TAGS_OFF, partial);
    loss_reduce<<<1, 64, 0, stream>>>(partial, out + LOSS_OFF);
}